// Round 5
// baseline (457.858 us; speedup 1.0000x reference)
//
#include <hip/hip_runtime.h>
#include <hip/hip_bf16.h>
#include <stdint.h>

// ---------------- problem constants ----------------
#define BATCH   16384
#define SDIM    128
#define ENCK    10
#define ADIM    32
#define DECK    10
#define HID     2048
#define KSPINE  1280      // SDIM*ENCK

typedef __bf16 bf16x8 __attribute__((ext_vector_type(8)));
typedef float  f32x4  __attribute__((ext_vector_type(4)));

typedef __attribute__((address_space(1))) const void kGlobalVoid;
typedef __attribute__((address_space(3))) void       kLdsVoid;

__device__ __forceinline__ unsigned short f2b(float f) {
  union { float f; unsigned u; } v; v.f = f;
  unsigned r = v.u + 0x7fffu + ((v.u >> 16) & 1u);   // RNE
  return (unsigned short)(r >> 16);
}

// ---------------- fp32 -> bf16 convert (2 elems/thread) ----------------
__global__ void f2b_kernel(const float* __restrict__ in, unsigned* __restrict__ out, int n2) {
  int i = blockIdx.x * blockDim.x + threadIdx.x;
  if (i >= n2) return;
  float2 v = reinterpret_cast<const float2*>(in)[i];
  out[i] = (unsigned)f2b(v.x) | ((unsigned)f2b(v.y) << 16);
}

// ---------------- encoder: sigmoid((x-mean)/std) -> bf16 spine ----------------
__global__ void encoder_kernel(const float* __restrict__ state,
                               const float* __restrict__ mean,
                               const float* __restrict__ stdv,
                               unsigned* __restrict__ spine) {
  int idx = blockIdx.x * blockDim.x + threadIdx.x;   // b*SDIM + d
  if (idx >= BATCH * SDIM) return;
  int d = idx & (SDIM - 1);
  float x = state[idx];
  float vals[ENCK];
#pragma unroll
  for (int k = 0; k < ENCK; ++k) {
    float z = (x - mean[d * ENCK + k]) / stdv[d * ENCK + k];
    vals[k] = 1.f / (1.f + __expf(-z));
  }
  unsigned* dst = spine + idx * (ENCK / 2);
#pragma unroll
  for (int k = 0; k < ENCK / 2; ++k)
    dst[k] = (unsigned)f2b(vals[2 * k]) | ((unsigned)f2b(vals[2 * k + 1]) << 16);
}

// ---------------- Weff/beff builders: fold grouped-conv into W3 ----------------
__global__ void weff_kernel(const float* __restrict__ W3, const float* __restrict__ Wd,
                            unsigned short* __restrict__ Weff) {
  int idx = blockIdx.x * 256 + threadIdx.x;   // a*2048 + j, 65536 total
  int a = idx >> 11, j = idx & 2047;
  float s = 0.f;
#pragma unroll
  for (int k = 0; k < DECK; ++k)
    s += Wd[a * DECK + k] * W3[(size_t)(a * DECK + k) * HID + j];
  Weff[idx] = f2b(s);
}

__global__ void beff_kernel(const float* __restrict__ b3, const float* __restrict__ Wd,
                            const float* __restrict__ bd, float* __restrict__ beff) {
  int a = threadIdx.x;
  if (a >= ADIM) return;
  float s = bd[a];
#pragma unroll
  for (int k = 0; k < DECK; ++k) s += Wd[a * DECK + k] * b3[a * DECK + k];
  beff[a] = s;
}

// ---------------- 256x256 4-wave bf16 GEMM (128x128 per wave) ----------------
// 256 thr = 4 waves (2x2), wave tile 128x128, acc[8][8] f32x4 (256 regs).
// Rationale: LDS read bytes/iter scale with sum of wave perimeters; 4 waves of
// 128x128 reads 262KB/iter vs 8 waves of 128x64 = 393KB (-33%) -> lower LDS floor.
// 4 phases/iter (phase = K-32 slice, 64 MFMA), shadow reads for p+1 during p.
// Stage schedule (iter i): P0: B1<-kt1 | P1: A0<-kt2 | P2: B0<-kt2 | P3: A1<-kt3.
// Every region overwritten >=1 phase + gload write-latency after last read.
// vmcnt(0) at P1 (waits A1@P3prev + B1@P0) and P3 (waits A0@P1 + B0@P2),
// placed AFTER the MFMA cluster so loads stay in flight across 2 barriers.

#define A0B 0
#define B0B 32768
#define A1B 65536
#define B1B 98304

#define FENCE asm volatile("" ::: "memory")

// stage one 32KB buffer (256 rows x 64 bf16) with 8 gload_lds x 256 thr x 16B
#define STAGE8(BASEPTR, R0, LDSB, KT)                                                        \
  _Pragma("unroll")                                                                          \
  for (int g = 0; g < 8; ++g) {                                                              \
    __builtin_amdgcn_global_load_lds(                                                        \
        (kGlobalVoid*)((BASEPTR) + (size_t)((R0) + g * 32 + rs) * K + (KT) + ce),            \
        (kLdsVoid*)(smem + (LDSB) + g * 4096 + t * 16), 16, 0, 0);                           \
  }

#define DS_AF8(DST, ABASE, KS)                                                               \
  _Pragma("unroll")                                                                          \
  for (int m = 0; m < 8; ++m) {                                                              \
    int rowl = wr * 128 + m * 16 + lr;                                                       \
    DST[m] = *reinterpret_cast<const bf16x8*>(                                               \
        smem + (ABASE) + rowl * 128 + ((((KS) << 6) | (kh << 4)) ^ swz));                    \
  }

#define DS_BF8(DST, BBASE, KS)                                                               \
  _Pragma("unroll")                                                                          \
  for (int n = 0; n < 8; ++n) {                                                              \
    int rowl = wc * 128 + n * 16 + lr;                                                       \
    DST[n] = *reinterpret_cast<const bf16x8*>(                                               \
        smem + (BBASE) + rowl * 128 + ((((KS) << 6) | (kh << 4)) ^ swz));                    \
  }

#define MFMA64(AF, BF)                                                                       \
  _Pragma("unroll")                                                                          \
  for (int m = 0; m < 8; ++m)                                                                \
    _Pragma("unroll")                                                                        \
    for (int n = 0; n < 8; ++n)                                                              \
      acc[m][n] = __builtin_amdgcn_mfma_f32_16x16x32_bf16(AF[m], BF[n], acc[m][n], 0, 0, 0);

#define PH4(AF_C, BF_C, AF_N, BF_N, SH_A, SH_B, SH_KS, DOVM, STG)                            \
  do {                                                                                       \
    asm volatile("s_waitcnt lgkmcnt(0)" ::: "memory");                                       \
    __builtin_amdgcn_sched_barrier(0);                                                       \
    __builtin_amdgcn_s_setprio(1);                                                           \
    MFMA64(AF_C, BF_C);                                                                      \
    __builtin_amdgcn_s_setprio(0);                                                           \
    if (DOVM) {                                                                              \
      asm volatile("s_waitcnt vmcnt(0)" ::: "memory");                                       \
      __builtin_amdgcn_sched_barrier(0);                                                     \
    }                                                                                        \
    DS_AF8(AF_N, SH_A, SH_KS);                                                               \
    DS_BF8(BF_N, SH_B, SH_KS);                                                               \
    STG;                                                                                     \
    FENCE;                                                                                   \
    __builtin_amdgcn_s_barrier();                                                            \
  } while (0)

__global__ __launch_bounds__(256, 1) void gemm256(
    const unsigned short* __restrict__ A,    // [M,K] bf16
    const unsigned short* __restrict__ Bw,   // [2048,K] bf16
    const float* __restrict__ bias,          // [2048]
    unsigned short* __restrict__ Cout,       // [M,2048] bf16
    int K, int NI) {                         // NI = K/128
  __shared__ char smem[131072];

  const int t    = threadIdx.x;              // 0..255
  const int lane = t & 63;
  const int w    = t >> 6;                   // 0..3
  const int wr   = w >> 1;                   // 0..1
  const int wc   = w & 1;                    // 0..1
  const int lr   = lane & 15;
  const int kh   = lane >> 4;                // 0..3
  const int swz  = (lr & 7) << 4;
  const int rs   = t >> 3;                   // stage row within 32-row band (0..31)
  const int ce   = ((t & 7) ^ (rs & 7)) << 3; // inverse-swizzled col (elements)

  // XCD-aware mapping: XCD owns an M-band x all 8 N-blocks (A fetched once per chip).
  const int bid = blockIdx.x;
  const int xcd = bid & 7, idx = bid >> 3;           // idx in [0,64)
  const int row0 = (xcd * 8 + (idx >> 3)) * 256;
  const int col0 = (idx & 7) * 256;

  f32x4 acc[8][8];
#pragma unroll
  for (int m = 0; m < 8; ++m)
#pragma unroll
    for (int n = 0; n < 8; ++n)
      acc[m][n] = (f32x4){0.f, 0.f, 0.f, 0.f};

  bf16x8 afc[8], afn[8], bfc[8], bfn[8];

  // ---- prologue: A0,B0 <- tile0 (k0..63); A1 <- tile1 (k64..127). B1 staged at P0. ----
  STAGE8(A,  row0, A0B, 0);
  STAGE8(Bw, col0, B0B, 0);
  STAGE8(A,  row0, A1B, 64);
  asm volatile("s_waitcnt vmcnt(8)" ::: "memory");   // retire A0,B0 (oldest 16)
  FENCE;
  __builtin_amdgcn_s_barrier();
  DS_AF8(afc, A0B, 0);
  DS_BF8(bfc, B0B, 0);

  for (int i = 0; i < NI; ++i) {
    int kt0 = i << 7;
    int kt1 = kt0 + 64;
    int kt2 = kt0 + 128; if (kt2 >= K) kt2 -= K;   // wrapped on last iter (data unused)
    int kt3 = kt0 + 192; if (kt3 >= K) kt3 -= K;

    PH4(afc, bfc, afn, bfn, A0B, B0B, 1, false, STAGE8(Bw, col0, B1B, kt1));
    PH4(afn, bfn, afc, bfc, A1B, B1B, 0, true,  STAGE8(A,  row0, A0B, kt2));
    PH4(afc, bfc, afn, bfn, A1B, B1B, 1, false, STAGE8(Bw, col0, B0B, kt2));
    PH4(afn, bfn, afc, bfc, A0B, B0B, 0, true,  STAGE8(A,  row0, A1B, kt3));
  }

  // ---- epilogue: bias + relu + bf16 store ----
#pragma unroll
  for (int m = 0; m < 8; ++m) {
    int gr0 = row0 + wr * 128 + m * 16 + kh * 4;
#pragma unroll
    for (int n = 0; n < 8; ++n) {
      int gc = col0 + wc * 128 + n * 16 + lr;
      float bv = bias[gc];
#pragma unroll
      for (int v = 0; v < 4; ++v) {
        float val = fmaxf(acc[m][n][v] + bv, 0.f);
        Cout[(size_t)(gr0 + v) * 2048 + gc] = f2b(val);
      }
    }
  }
}

// ---------------- skinny GEMM3 + tanh: [16384,2048]x[32,2048]^T -> d_out ----------------
// 16 rows/wave, 1024 waves for latency tolerance; HBM-bound.
__global__ __launch_bounds__(128) void gemm_skinny(
    const unsigned short* __restrict__ A,    // h2 [16384,2048] bf16
    const unsigned short* __restrict__ Bw,   // Weff [32,2048] bf16
    const float* __restrict__ beff,          // [32]
    float* __restrict__ out) {               // [16384,32] fp32
  const int t = threadIdx.x, lane = t & 63, w = t >> 6;
  const int lr = lane & 15, kh = lane >> 4;
  const int row0 = (blockIdx.x * 2 + w) * 16;
  f32x4 acc[2];
  acc[0] = (f32x4){0.f, 0.f, 0.f, 0.f};
  acc[1] = (f32x4){0.f, 0.f, 0.f, 0.f};

  const unsigned short* Arow = A  + (size_t)(row0 + lr) * HID + kh * 8;
  const unsigned short* B0   = Bw + (size_t)(lr) * HID + kh * 8;
  const unsigned short* B1   = Bw + (size_t)(16 + lr) * HID + kh * 8;

#pragma unroll 4
  for (int kt = 0; kt < HID; kt += 32) {
    bf16x8 a  = *reinterpret_cast<const bf16x8*>(Arow + kt);
    bf16x8 b0 = *reinterpret_cast<const bf16x8*>(B0 + kt);
    bf16x8 b1 = *reinterpret_cast<const bf16x8*>(B1 + kt);
    acc[0] = __builtin_amdgcn_mfma_f32_16x16x32_bf16(a, b0, acc[0], 0, 0, 0);
    acc[1] = __builtin_amdgcn_mfma_f32_16x16x32_bf16(a, b1, acc[1], 0, 0, 0);
  }
#pragma unroll
  for (int n = 0; n < 2; ++n)
#pragma unroll
    for (int v = 0; v < 4; ++v) {
      int row = row0 + kh * 4 + v;
      int col = n * 16 + lr;
      out[(size_t)row * ADIM + col] = tanhf(acc[n][v] + beff[col]);
    }
}

// ---------------- launch ----------------
extern "C" void kernel_launch(void* const* d_in, const int* in_sizes, int n_in,
                              void* d_out, int out_size, void* d_ws, size_t ws_size,
                              hipStream_t stream) {
  const float* state    = (const float*)d_in[0];
  const float* mean_enc = (const float*)d_in[1];
  const float* std_enc  = (const float*)d_in[2];
  const float* W1 = (const float*)d_in[3];
  const float* b1 = (const float*)d_in[4];
  const float* W2 = (const float*)d_in[5];
  const float* b2 = (const float*)d_in[6];
  const float* W3 = (const float*)d_in[7];
  const float* b3 = (const float*)d_in[8];
  const float* Wd = (const float*)d_in[9];
  const float* bd = (const float*)d_in[10];

  char* ws = (char*)d_ws;
  unsigned short* W1b   = (unsigned short*)(ws + 0);           //  5,242,880
  unsigned short* W2b   = (unsigned short*)(ws + 5242880);     //  8,388,608
  unsigned short* Weff  = (unsigned short*)(ws + 13631488);    //    131,072
  float*          beff  = (float*)(ws + 13762560);             //        128
  unsigned short* spine = (unsigned short*)(ws + 13762688);    // 41,943,040
  unsigned short* h1    = (unsigned short*)(ws + 55705728);    // 67,108,864
  unsigned short* h2    = (unsigned short*)(ws + 122814592);   // 67,108,864 -> end ~190MB

  // weight preprocessing
  f2b_kernel<<<5120, 256, 0, stream>>>(W1, (unsigned*)W1b, 1310720);
  f2b_kernel<<<8192, 256, 0, stream>>>(W2, (unsigned*)W2b, 2097152);
  weff_kernel<<<256, 256, 0, stream>>>(W3, Wd, Weff);
  beff_kernel<<<1, 64, 0, stream>>>(b3, Wd, bd, beff);

  // encoder
  encoder_kernel<<<(BATCH * SDIM) / 256, 256, 0, stream>>>(state, mean_enc, std_enc, (unsigned*)spine);

  // GEMM chain
  gemm256<<<512, 256, 0, stream>>>(spine, W1b, b1, h1, KSPINE, KSPINE / 128);
  gemm256<<<512, 256, 0, stream>>>(h1,    W2b, b2, h2, HID,    HID / 128);
  gemm_skinny<<<BATCH / 32, 128, 0, stream>>>(h2, Weff, beff, (float*)d_out);
}

// Round 6
// 380.175 us; speedup vs baseline: 1.2043x; 1.2043x over previous
//
#include <hip/hip_runtime.h>
#include <hip/hip_bf16.h>
#include <stdint.h>

// ---------------- problem constants ----------------
#define BATCH   16384
#define SDIM    128
#define ENCK    10
#define ADIM    32
#define DECK    10
#define HID     2048
#define KSPINE  1280      // SDIM*ENCK

typedef __bf16 bf16x8 __attribute__((ext_vector_type(8)));
typedef float  f32x4  __attribute__((ext_vector_type(4)));

typedef __attribute__((address_space(1))) const void kGlobalVoid;
typedef __attribute__((address_space(3))) void       kLdsVoid;

__device__ __forceinline__ unsigned short f2b(float f) {
  union { float f; unsigned u; } v; v.f = f;
  unsigned r = v.u + 0x7fffu + ((v.u >> 16) & 1u);   // RNE
  return (unsigned short)(r >> 16);
}

// ---------------- fp32 -> bf16 convert (2 elems/thread) ----------------
__global__ void f2b_kernel(const float* __restrict__ in, unsigned* __restrict__ out, int n2) {
  int i = blockIdx.x * blockDim.x + threadIdx.x;
  if (i >= n2) return;
  float2 v = reinterpret_cast<const float2*>(in)[i];
  out[i] = (unsigned)f2b(v.x) | ((unsigned)f2b(v.y) << 16);
}

// ---------------- encoder: sigmoid((x-mean)/std) -> bf16 spine ----------------
__global__ void encoder_kernel(const float* __restrict__ state,
                               const float* __restrict__ mean,
                               const float* __restrict__ stdv,
                               unsigned* __restrict__ spine) {
  int idx = blockIdx.x * blockDim.x + threadIdx.x;   // b*SDIM + d
  if (idx >= BATCH * SDIM) return;
  int d = idx & (SDIM - 1);
  float x = state[idx];
  float vals[ENCK];
#pragma unroll
  for (int k = 0; k < ENCK; ++k) {
    float z = (x - mean[d * ENCK + k]) / stdv[d * ENCK + k];
    vals[k] = 1.f / (1.f + __expf(-z));
  }
  unsigned* dst = spine + idx * (ENCK / 2);
#pragma unroll
  for (int k = 0; k < ENCK / 2; ++k)
    dst[k] = (unsigned)f2b(vals[2 * k]) | ((unsigned)f2b(vals[2 * k + 1]) << 16);
}

// ---------------- Weff/beff builders: fold grouped-conv into W3 ----------------
__global__ void weff_kernel(const float* __restrict__ W3, const float* __restrict__ Wd,
                            unsigned short* __restrict__ Weff) {
  int idx = blockIdx.x * 256 + threadIdx.x;   // a*2048 + j, 65536 total
  int a = idx >> 11, j = idx & 2047;
  float s = 0.f;
#pragma unroll
  for (int k = 0; k < DECK; ++k)
    s += Wd[a * DECK + k] * W3[(size_t)(a * DECK + k) * HID + j];
  Weff[idx] = f2b(s);
}

__global__ void beff_kernel(const float* __restrict__ b3, const float* __restrict__ Wd,
                            const float* __restrict__ bd, float* __restrict__ beff) {
  int a = threadIdx.x;
  if (a >= ADIM) return;
  float s = bd[a];
#pragma unroll
  for (int k = 0; k < DECK; ++k) s += Wd[a * DECK + k] * b3[a * DECK + k];
  beff[a] = s;
}

// ---------------- 256x256 bf16 GEMM: A via LDS, B direct global->reg ----------------
// 512 thr = 8 waves (2M x 4N), wave tile 128x64, acc[8][4] (128 VGPR).
// B (weights) never touches LDS: per-lane fragment loads from L2 (k-slices are
// L2-resident under lockstep iteration). LDS = A only, 2 x 32KB half-K buffers.
// LDS traffic/iter: 256KB reads + 64KB writes (~3.8k cy) < MFMA floor (~5.0k cy).
// 8 phases/iter (4 per K-64 half, phase = m-pair), shadow ds_reads for p+1 in p.
// Per half h: p0 issues {stage A(h+1) -> other buf (4 gload_lds), B(h+1) -> regs (8)}
// BEFORE the MFMA cluster (compiler's exact vmcnt wait for current B covers order);
// manual vmcnt(8) at p2 retires the staging (B loads newer, stay in flight);
// p3's shadow reads then safely hit the new buffer after p2's barrier.
// Buffer overwrite at p0 is >=2 barriers after that buffer's last ds_read.

#define A0B 0
#define A1B 32768

#define FENCE asm volatile("" ::: "memory")

// stage one 32KB A buffer (256 rows x 64 bf16) : 4 gload_lds x 512 thr x 16B
#define STAGE4(R0, LDSB, KT)                                                                 \
  _Pragma("unroll")                                                                          \
  for (int g = 0; g < 4; ++g) {                                                              \
    __builtin_amdgcn_global_load_lds(                                                        \
        (kGlobalVoid*)(A + (size_t)((R0) + g * 64 + rs) * K + (KT) + ce),                    \
        (kLdsVoid*)(smem + (LDSB) + g * 8192 + t * 16), 16, 0, 0);                           \
  }

// B fragments for one K-64 half, straight from global (fragment layout addressing)
#define GLB_BF(DST, KT)                                                                      \
  _Pragma("unroll")                                                                          \
  for (int n = 0; n < 4; ++n) {                                                              \
    _Pragma("unroll")                                                                        \
    for (int ks = 0; ks < 2; ++ks) {                                                         \
      DST[n][ks] = *reinterpret_cast<const bf16x8*>(Bbase + (size_t)n * 16 * K + (KT) + ks * 32); \
    }                                                                                        \
  }

#define DS_AF(DST, ABASE, MPN)                                                               \
  _Pragma("unroll")                                                                          \
  for (int j2 = 0; j2 < 2; ++j2) {                                                           \
    _Pragma("unroll")                                                                        \
    for (int ks = 0; ks < 2; ++ks) {                                                         \
      int rowl = wr * 128 + (MPN) * 32 + j2 * 16 + lr;                                       \
      DST[j2][ks] = *reinterpret_cast<const bf16x8*>(                                        \
          smem + (ABASE) + rowl * 128 + ((((ks) << 6) | (kh << 4)) ^ swz));                  \
    }                                                                                        \
  }

#define MFMA16(MP, AF, BF)                                                                   \
  _Pragma("unroll")                                                                          \
  for (int j2 = 0; j2 < 2; ++j2)                                                             \
    _Pragma("unroll")                                                                        \
    for (int n = 0; n < 4; ++n)                                                              \
      _Pragma("unroll")                                                                      \
      for (int ks = 0; ks < 2; ++ks)                                                         \
        acc[(MP) * 2 + j2][n] = __builtin_amdgcn_mfma_f32_16x16x32_bf16(                     \
            AF[j2][ks], BF[n][ks], acc[(MP) * 2 + j2][n], 0, 0, 0);

// p0 of a half: issue next-half stage + B loads, then MFMA mp0, shadow-read mp1
#define PH_P0(AF_C, AF_N, BF_C, BF_N, CURB, NXTB, KTN)                                       \
  do {                                                                                       \
    asm volatile("s_waitcnt lgkmcnt(0)" ::: "memory");                                       \
    __builtin_amdgcn_sched_barrier(0);                                                       \
    STAGE4(row0, NXTB, KTN);                                                                 \
    GLB_BF(BF_N, KTN);                                                                       \
    FENCE;                                                                                   \
    __builtin_amdgcn_s_setprio(1);                                                           \
    MFMA16(0, AF_C, BF_C);                                                                   \
    __builtin_amdgcn_s_setprio(0);                                                           \
    DS_AF(AF_N, CURB, 1);                                                                    \
    FENCE;                                                                                   \
    __builtin_amdgcn_s_barrier();                                                            \
  } while (0)

// p1/p2/p3: MFMA mp, shadow-read next m-pair (RD_MP) from RDB; optional vmcnt(8)
#define PH_PLAIN(MP, AF_C, AF_N, BF_C, RDB, RD_MP, DOVM)                                     \
  do {                                                                                       \
    asm volatile("s_waitcnt lgkmcnt(0)" ::: "memory");                                       \
    __builtin_amdgcn_sched_barrier(0);                                                       \
    __builtin_amdgcn_s_setprio(1);                                                           \
    MFMA16(MP, AF_C, BF_C);                                                                  \
    __builtin_amdgcn_s_setprio(0);                                                           \
    if (DOVM) {                                                                              \
      asm volatile("s_waitcnt vmcnt(8)" ::: "memory");                                       \
      __builtin_amdgcn_sched_barrier(0);                                                     \
    }                                                                                        \
    DS_AF(AF_N, RDB, RD_MP);                                                                 \
    FENCE;                                                                                   \
    __builtin_amdgcn_s_barrier();                                                            \
  } while (0)

__global__ __launch_bounds__(512, 2) void gemm256(
    const unsigned short* __restrict__ A,    // [M,K] bf16
    const unsigned short* __restrict__ Bw,   // [2048,K] bf16
    const float* __restrict__ bias,          // [2048]
    unsigned short* __restrict__ Cout,       // [M,2048] bf16
    int K, int NI) {                         // NI = K/128
  __shared__ char smem[65536];

  const int t    = threadIdx.x;
  const int lane = t & 63;
  const int w    = t >> 6;
  const int wr   = w >> 2;      // 0..1
  const int wc   = w & 3;       // 0..3
  const int lr   = lane & 15;
  const int kh   = lane >> 4;   // 0..3
  const int swz  = (lr & 7) << 4;
  const int rs   = t >> 3;                      // stage row within 64-row band
  const int ce   = ((t & 7) ^ (rs & 7)) << 3;   // inverse-swizzled col (elements)

  // XCD-aware mapping: XCD owns an M-band x all 8 N-blocks (A fetched once per chip).
  const int bid = blockIdx.x;
  const int xcd = bid & 7, idx = bid >> 3;           // idx in [0,64)
  const int row0 = (xcd * 8 + (idx >> 3)) * 256;
  const int col0 = (idx & 7) * 256;

  const unsigned short* Bbase = Bw + (size_t)(col0 + wc * 64 + lr) * K + kh * 8;

  f32x4 acc[8][4];
#pragma unroll
  for (int m = 0; m < 8; ++m)
#pragma unroll
    for (int n = 0; n < 4; ++n)
      acc[m][n] = (f32x4){0.f, 0.f, 0.f, 0.f};

  bf16x8 afc[2][2], afn[2][2], bfc[4][2], bfn[4][2];

  // ---- prologue: A h0 -> buf0, B h0 -> bfc ----
  STAGE4(row0, A0B, 0);
  GLB_BF(bfc, 0);
  asm volatile("s_waitcnt vmcnt(8)" ::: "memory");   // retire the 4 staging loads
  FENCE;
  __builtin_amdgcn_s_barrier();
  DS_AF(afc, A0B, 0);

  for (int i = 0; i < NI; ++i) {
    int kt0 = i << 7;
    int kt1 = kt0 + 64;
    int kt2 = kt0 + 128; if (kt2 >= K) kt2 = 0;    // wrapped on last iter (data unused)

    // half 0: buf0, bfc ; prefetch h1 -> buf1, bfn
    PH_P0 (   afc, afn, bfc, bfn, A0B, A1B, kt1);
    PH_PLAIN(1, afn, afc, bfc, A0B, 2, false);
    PH_PLAIN(2, afc, afn, bfc, A0B, 3, true);
    PH_PLAIN(3, afn, afc, bfc, A1B, 0, false);
    // half 1: buf1, bfn ; prefetch next h0 -> buf0, bfc
    PH_P0 (   afc, afn, bfn, bfc, A1B, A0B, kt2);
    PH_PLAIN(1, afn, afc, bfn, A1B, 2, false);
    PH_PLAIN(2, afc, afn, bfn, A1B, 3, true);
    PH_PLAIN(3, afn, afc, bfn, A0B, 0, false);
  }

  // ---- epilogue: bias + relu + bf16 store ----
#pragma unroll
  for (int m = 0; m < 8; ++m) {
    int gr0 = row0 + wr * 128 + m * 16 + kh * 4;
#pragma unroll
    for (int n = 0; n < 4; ++n) {
      int gc = col0 + wc * 64 + n * 16 + lr;
      float bv = bias[gc];
#pragma unroll
      for (int v = 0; v < 4; ++v) {
        float val = fmaxf(acc[m][n][v] + bv, 0.f);
        Cout[(size_t)(gr0 + v) * 2048 + gc] = f2b(val);
      }
    }
  }
}

// ---------------- skinny GEMM3 + tanh: [16384,2048]x[32,2048]^T -> d_out ----------------
// 16 rows/wave, 1024 waves for latency tolerance; HBM-bound.
__global__ __launch_bounds__(128) void gemm_skinny(
    const unsigned short* __restrict__ A,    // h2 [16384,2048] bf16
    const unsigned short* __restrict__ Bw,   // Weff [32,2048] bf16
    const float* __restrict__ beff,          // [32]
    float* __restrict__ out) {               // [16384,32] fp32
  const int t = threadIdx.x, lane = t & 63, w = t >> 6;
  const int lr = lane & 15, kh = lane >> 4;
  const int row0 = (blockIdx.x * 2 + w) * 16;
  f32x4 acc[2];
  acc[0] = (f32x4){0.f, 0.f, 0.f, 0.f};
  acc[1] = (f32x4){0.f, 0.f, 0.f, 0.f};

  const unsigned short* Arow = A  + (size_t)(row0 + lr) * HID + kh * 8;
  const unsigned short* B0   = Bw + (size_t)(lr) * HID + kh * 8;
  const unsigned short* B1   = Bw + (size_t)(16 + lr) * HID + kh * 8;

#pragma unroll 4
  for (int kt = 0; kt < HID; kt += 32) {
    bf16x8 a  = *reinterpret_cast<const bf16x8*>(Arow + kt);
    bf16x8 b0 = *reinterpret_cast<const bf16x8*>(B0 + kt);
    bf16x8 b1 = *reinterpret_cast<const bf16x8*>(B1 + kt);
    acc[0] = __builtin_amdgcn_mfma_f32_16x16x32_bf16(a, b0, acc[0], 0, 0, 0);
    acc[1] = __builtin_amdgcn_mfma_f32_16x16x32_bf16(a, b1, acc[1], 0, 0, 0);
  }
#pragma unroll
  for (int n = 0; n < 2; ++n)
#pragma unroll
    for (int v = 0; v < 4; ++v) {
      int row = row0 + kh * 4 + v;
      int col = n * 16 + lr;
      out[(size_t)row * ADIM + col] = tanhf(acc[n][v] + beff[col]);
    }
}

// ---------------- launch ----------------
extern "C" void kernel_launch(void* const* d_in, const int* in_sizes, int n_in,
                              void* d_out, int out_size, void* d_ws, size_t ws_size,
                              hipStream_t stream) {
  const float* state    = (const float*)d_in[0];
  const float* mean_enc = (const float*)d_in[1];
  const float* std_enc  = (const float*)d_in[2];
  const float* W1 = (const float*)d_in[3];
  const float* b1 = (const float*)d_in[4];
  const float* W2 = (const float*)d_in[5];
  const float* b2 = (const float*)d_in[6];
  const float* W3 = (const float*)d_in[7];
  const float* b3 = (const float*)d_in[8];
  const float* Wd = (const float*)d_in[9];
  const float* bd = (const float*)d_in[10];

  char* ws = (char*)d_ws;
  unsigned short* W1b   = (unsigned short*)(ws + 0);           //  5,242,880
  unsigned short* W2b   = (unsigned short*)(ws + 5242880);     //  8,388,608
  unsigned short* Weff  = (unsigned short*)(ws + 13631488);    //    131,072
  float*          beff  = (float*)(ws + 13762560);             //        128
  unsigned short* spine = (unsigned short*)(ws + 13762688);    // 41,943,040
  unsigned short* h1    = (unsigned short*)(ws + 55705728);    // 67,108,864
  unsigned short* h2    = (unsigned short*)(ws + 122814592);   // 67,108,864 -> end ~190MB

  // weight preprocessing
  f2b_kernel<<<5120, 256, 0, stream>>>(W1, (unsigned*)W1b, 1310720);
  f2b_kernel<<<8192, 256, 0, stream>>>(W2, (unsigned*)W2b, 2097152);
  weff_kernel<<<256, 256, 0, stream>>>(W3, Wd, Weff);
  beff_kernel<<<1, 64, 0, stream>>>(b3, Wd, bd, beff);

  // encoder
  encoder_kernel<<<(BATCH * SDIM) / 256, 256, 0, stream>>>(state, mean_enc, std_enc, (unsigned*)spine);

  // GEMM chain
  gemm256<<<512, 512, 0, stream>>>(spine, W1b, b1, h1, KSPINE, KSPINE / 128);
  gemm256<<<512, 512, 0, stream>>>(h1,    W2b, b2, h2, HID,    HID / 128);
  gemm_skinny<<<BATCH / 32, 128, 0, stream>>>(h2, Weff, beff, (float*)d_out);
}

// Round 7
// 249.077 us; speedup vs baseline: 1.8382x; 1.5263x over previous
//
#include <hip/hip_runtime.h>
#include <hip/hip_bf16.h>
#include <stdint.h>

// ---------------- problem constants ----------------
#define BATCH   16384
#define SDIM    128
#define ENCK    10
#define ADIM    32
#define DECK    10
#define HID     2048
#define KSPINE  1280      // SDIM*ENCK

typedef __bf16 bf16x8 __attribute__((ext_vector_type(8)));
typedef float  f32x4  __attribute__((ext_vector_type(4)));

typedef __attribute__((address_space(1))) const void kGlobalVoid;
typedef __attribute__((address_space(3))) void       kLdsVoid;

__device__ __forceinline__ unsigned short f2b(float f) {
  union { float f; unsigned u; } v; v.f = f;
  unsigned r = v.u + 0x7fffu + ((v.u >> 16) & 1u);   // RNE
  return (unsigned short)(r >> 16);
}

// ---------------- fp32 -> bf16 convert (2 elems/thread) ----------------
__global__ void f2b_kernel(const float* __restrict__ in, unsigned* __restrict__ out, int n2) {
  int i = blockIdx.x * blockDim.x + threadIdx.x;
  if (i >= n2) return;
  float2 v = reinterpret_cast<const float2*>(in)[i];
  out[i] = (unsigned)f2b(v.x) | ((unsigned)f2b(v.y) << 16);
}

// ---------------- encoder: sigmoid((x-mean)/std) -> bf16 spine ----------------
__global__ void encoder_kernel(const float* __restrict__ state,
                               const float* __restrict__ mean,
                               const float* __restrict__ stdv,
                               unsigned* __restrict__ spine) {
  int idx = blockIdx.x * blockDim.x + threadIdx.x;   // b*SDIM + d
  if (idx >= BATCH * SDIM) return;
  int d = idx & (SDIM - 1);
  float x = state[idx];
  float vals[ENCK];
#pragma unroll
  for (int k = 0; k < ENCK; ++k) {
    float z = (x - mean[d * ENCK + k]) / stdv[d * ENCK + k];
    vals[k] = 1.f / (1.f + __expf(-z));
  }
  unsigned* dst = spine + idx * (ENCK / 2);
#pragma unroll
  for (int k = 0; k < ENCK / 2; ++k)
    dst[k] = (unsigned)f2b(vals[2 * k]) | ((unsigned)f2b(vals[2 * k + 1]) << 16);
}

// ---------------- Weff/beff builders: fold grouped-conv into W3 ----------------
__global__ void weff_kernel(const float* __restrict__ W3, const float* __restrict__ Wd,
                            unsigned short* __restrict__ Weff) {
  int idx = blockIdx.x * 256 + threadIdx.x;   // a*2048 + j, 65536 total
  int a = idx >> 11, j = idx & 2047;
  float s = 0.f;
#pragma unroll
  for (int k = 0; k < DECK; ++k)
    s += Wd[a * DECK + k] * W3[(size_t)(a * DECK + k) * HID + j];
  Weff[idx] = f2b(s);
}

__global__ void beff_kernel(const float* __restrict__ b3, const float* __restrict__ Wd,
                            const float* __restrict__ bd, float* __restrict__ beff) {
  int a = threadIdx.x;
  if (a >= ADIM) return;
  float s = bd[a];
#pragma unroll
  for (int k = 0; k < DECK; ++k) s += Wd[a * DECK + k] * b3[a * DECK + k];
  beff[a] = s;
}

// ---------------- 256x256 8-phase bf16 GEMM (R4 + balanced B reads + T19) ----------------
// 512 thr = 8 waves (2M x 4N), wave tile 128x64, acc[8][4].
// Per phase: 16 MFMA + 4 A-shadow ds_reads + 2 B-gradual ds_reads + 1 STAGE(2 gload_lds),
// interleaved via sched_group_barrier so LDS reads hide under the matrix pipe.
// B frags for half h+1 are read 2/phase during half h (balanced; no p3/p7 spike).
// vmcnt ledger (steady state, 2 loads/phase): enter p0 with {p4',p5',p6',p7'}=8.
//   p0: vmcnt(2) retires p4',p5',p6'  (B1B complete for gradual reads; A0B q1q3)
//   p3: vmcnt(6) retires p7'          (A1B q0q2 for p3's mp0 shadow read)
//   p4: vmcnt(2) retires p0,p1,p2     (B0B complete; A1B q1q3)
//   p7: vmcnt(6) retires p3           (A0B q0q2 for p7's mp0 shadow read)
// Overwrite discipline: every LDS band is overwritten >=2 barriers after last read.

#define A0B 0
#define B0B 32768
#define A1B 65536
#define B1B 98304

#define FENCE asm volatile("" ::: "memory")

#define STAGE(BASEPTR, R0A, R0B, LDS0, LDS1, KT)                                             \
  __builtin_amdgcn_global_load_lds((kGlobalVoid*)((BASEPTR) + (size_t)((R0A) + rs) * K + (KT) + ce), \
                                   (kLdsVoid*)(smem + (LDS0) + t * 16), 16, 0, 0);           \
  __builtin_amdgcn_global_load_lds((kGlobalVoid*)((BASEPTR) + (size_t)((R0B) + rs) * K + (KT) + ce), \
                                   (kLdsVoid*)(smem + (LDS1) + t * 16), 16, 0, 0);

#define DS_AF(DST, ABASE, MPN)                                                               \
  _Pragma("unroll")                                                                          \
  for (int j2 = 0; j2 < 2; ++j2) {                                                           \
    _Pragma("unroll")                                                                        \
    for (int ks = 0; ks < 2; ++ks) {                                                         \
      int rowl = wr * 128 + (MPN) * 32 + j2 * 16 + lr;                                       \
      DST[j2][ks] = *reinterpret_cast<const bf16x8*>(                                        \
          smem + (ABASE) + rowl * 128 + ((((ks) << 6) | (kh << 4)) ^ swz));                  \
    }                                                                                        \
  }

// read B frag pair n=NP (both ks) for the NEXT half
#define DS_B2(DST, NP, BBASE)                                                                \
  _Pragma("unroll")                                                                          \
  for (int ks = 0; ks < 2; ++ks) {                                                           \
    int rowl = wc * 64 + (NP) * 16 + lr;                                                     \
    DST[NP][ks] = *reinterpret_cast<const bf16x8*>(                                          \
        smem + (BBASE) + rowl * 128 + ((((ks) << 6) | (kh << 4)) ^ swz));                    \
  }

// all 8 B frags (prologue only)
#define DS_BF(DST, BBASE)                                                                    \
  _Pragma("unroll")                                                                          \
  for (int n = 0; n < 4; ++n) {                                                              \
    _Pragma("unroll")                                                                        \
    for (int ks = 0; ks < 2; ++ks) {                                                         \
      int rowl = wc * 64 + n * 16 + lr;                                                      \
      DST[n][ks] = *reinterpret_cast<const bf16x8*>(                                         \
          smem + (BBASE) + rowl * 128 + ((((ks) << 6) | (kh << 4)) ^ swz));                  \
    }                                                                                        \
  }

#define MFMA16(MP, AF, BF)                                                                   \
  _Pragma("unroll")                                                                          \
  for (int j2 = 0; j2 < 2; ++j2)                                                             \
    _Pragma("unroll")                                                                        \
    for (int n = 0; n < 4; ++n)                                                              \
      _Pragma("unroll")                                                                      \
      for (int ks = 0; ks < 2; ++ks)                                                         \
        acc[(MP) * 2 + j2][n] = __builtin_amdgcn_mfma_f32_16x16x32_bf16(                     \
            AF[j2][ks], BF[n][ks], acc[(MP) * 2 + j2][n], 0, 0, 0);

// T19: interleave 16 MFMA with 6 ds_reads + 2 gload_lds inside the phase region
#define SGB_PHASE                                                                            \
  __builtin_amdgcn_sched_group_barrier(0x8, 2, 0);                                           \
  __builtin_amdgcn_sched_group_barrier(0x100, 1, 0);                                         \
  __builtin_amdgcn_sched_group_barrier(0x8, 2, 0);                                           \
  __builtin_amdgcn_sched_group_barrier(0x100, 1, 0);                                         \
  __builtin_amdgcn_sched_group_barrier(0x20, 2, 0);                                          \
  __builtin_amdgcn_sched_group_barrier(0x8, 3, 0);                                           \
  __builtin_amdgcn_sched_group_barrier(0x100, 1, 0);                                         \
  __builtin_amdgcn_sched_group_barrier(0x8, 3, 0);                                           \
  __builtin_amdgcn_sched_group_barrier(0x100, 1, 0);                                         \
  __builtin_amdgcn_sched_group_barrier(0x8, 3, 0);                                           \
  __builtin_amdgcn_sched_group_barrier(0x100, 1, 0);                                         \
  __builtin_amdgcn_sched_group_barrier(0x8, 3, 0);                                           \
  __builtin_amdgcn_sched_group_barrier(0x100, 1, 0);

#define VM_NONE
#define VM2 asm volatile("s_waitcnt vmcnt(2)" ::: "memory"); __builtin_amdgcn_sched_barrier(0);
#define VM6 asm volatile("s_waitcnt vmcnt(6)" ::: "memory"); __builtin_amdgcn_sched_barrier(0);

#define PH(MP, AF_C, AF_N, BF_C, BF_N, NXT_A, NXT_MP, BBASE_N, VMW, STG)                     \
  do {                                                                                       \
    asm volatile("s_waitcnt lgkmcnt(0)" ::: "memory");                                       \
    __builtin_amdgcn_sched_barrier(0);                                                       \
    VMW                                                                                      \
    __builtin_amdgcn_s_setprio(1);                                                           \
    MFMA16(MP, AF_C, BF_C);                                                                  \
    __builtin_amdgcn_s_setprio(0);                                                           \
    DS_AF(AF_N, NXT_A, NXT_MP);                                                              \
    DS_B2(BF_N, MP, BBASE_N);                                                                \
    STG;                                                                                     \
    SGB_PHASE;                                                                               \
    FENCE;                                                                                   \
    __builtin_amdgcn_s_barrier();                                                            \
  } while (0)

__global__ __launch_bounds__(512, 2) void gemm256(
    const unsigned short* __restrict__ A,    // [M,K] bf16
    const unsigned short* __restrict__ Bw,   // [2048,K] bf16
    const float* __restrict__ bias,          // [2048]
    unsigned short* __restrict__ Cout,       // [M,2048] bf16
    int K, int NI) {                         // NI = K/128
  __shared__ char smem[131072];

  const int t    = threadIdx.x;
  const int lane = t & 63;
  const int w    = t >> 6;
  const int wr   = w >> 2;      // 0..1
  const int wc   = w & 3;       // 0..3
  const int lr   = lane & 15;
  const int kh   = lane >> 4;   // 0..3
  const int swz  = (lr & 7) << 4;
  const int rs   = t >> 3;                      // stage row within 64-row band
  const int ce   = ((t & 7) ^ (rs & 7)) << 3;   // inverse-swizzled col (elements)

  // XCD-aware mapping: XCD owns an M-band x all 8 N-blocks (A fetched once per chip).
  const int bid = blockIdx.x;
  const int xcd = bid & 7, idx = bid >> 3;           // idx in [0,64)
  const int row0 = (xcd * 8 + (idx >> 3)) * 256;
  const int col0 = (idx & 7) * 256;

  f32x4 acc[8][4];
#pragma unroll
  for (int m = 0; m < 8; ++m)
#pragma unroll
    for (int n = 0; n < 4; ++n)
      acc[m][n] = (f32x4){0.f, 0.f, 0.f, 0.f};

  bf16x8 afc[2][2], afn[2][2], bfA[4][2], bfB[4][2];

  // ---- prologue: B0<-k0..63, A0<-k0..127, B1<-k64..127, A1 q0q2<-k64 ----
  STAGE(Bw, col0 + 0,   col0 + 64,  B0B + 0,     B0B + 8192,  0);
  STAGE(Bw, col0 + 128, col0 + 192, B0B + 16384, B0B + 24576, 0);
  STAGE(A,  row0 + 0,   row0 + 128, A0B + 0,     A0B + 16384, 0);
  STAGE(A,  row0 + 64,  row0 + 192, A0B + 8192,  A0B + 24576, 0);
  STAGE(Bw, col0 + 0,   col0 + 64,  B1B + 0,     B1B + 8192,  64);
  STAGE(Bw, col0 + 128, col0 + 192, B1B + 16384, B1B + 24576, 64);
  STAGE(A,  row0 + 0,   row0 + 128, A1B + 0,     A1B + 16384, 64);
  asm volatile("s_waitcnt vmcnt(0)" ::: "memory");
  FENCE;
  __builtin_amdgcn_s_barrier();
  DS_AF(afc, A0B, 0);     // mp0 for p0
  DS_BF(bfA, B0B);        // full B for half0 (B0B overwritten from p1 on)

  for (int i = 0; i < NI; ++i) {
    int kt0 = i << 7;
    int kt1 = kt0 + 64;
    int kt2 = kt0 + 128; if (kt2 >= K) kt2 -= K;   // wrapped on last iter (data unused)
    int kt3 = kt0 + 192; if (kt3 >= K) kt3 -= K;

    // half0: A0B + bfA ; prefetch bfB from B1B, A shadow, stages
    PH(0, afc, afn, bfA, bfB, A0B, 1, B1B, VM2,
       STAGE(A,  row0 + 64,  row0 + 192, A1B + 8192,  A1B + 24576, kt1));
    PH(1, afn, afc, bfA, bfB, A0B, 2, B1B, VM_NONE,
       STAGE(Bw, col0 + 0,   col0 + 64,  B0B + 0,     B0B + 8192,  kt2));
    PH(2, afc, afn, bfA, bfB, A0B, 3, B1B, VM_NONE,
       STAGE(Bw, col0 + 128, col0 + 192, B0B + 16384, B0B + 24576, kt2));
    PH(3, afn, afc, bfA, bfB, A1B, 0, B1B, VM6,
       STAGE(A,  row0 + 0,   row0 + 128, A0B + 0,     A0B + 16384, kt2));
    // half1: A1B + bfB ; prefetch bfA (next iter) from B0B
    PH(0, afc, afn, bfB, bfA, A1B, 1, B0B, VM2,
       STAGE(A,  row0 + 64,  row0 + 192, A0B + 8192,  A0B + 24576, kt2));
    PH(1, afn, afc, bfB, bfA, A1B, 2, B0B, VM_NONE,
       STAGE(Bw, col0 + 0,   col0 + 64,  B1B + 0,     B1B + 8192,  kt3));
    PH(2, afc, afn, bfB, bfA, A1B, 3, B0B, VM_NONE,
       STAGE(Bw, col0 + 128, col0 + 192, B1B + 16384, B1B + 24576, kt3));
    PH(3, afn, afc, bfB, bfA, A0B, 0, B0B, VM6,
       STAGE(A,  row0 + 0,   row0 + 128, A1B + 0,     A1B + 16384, kt3));
  }

  // ---- epilogue: bias + relu + bf16 store ----
#pragma unroll
  for (int m = 0; m < 8; ++m) {
    int gr0 = row0 + wr * 128 + m * 16 + kh * 4;
#pragma unroll
    for (int n = 0; n < 4; ++n) {
      int gc = col0 + wc * 64 + n * 16 + lr;
      float bv = bias[gc];
#pragma unroll
      for (int v = 0; v < 4; ++v) {
        float val = fmaxf(acc[m][n][v] + bv, 0.f);
        Cout[(size_t)(gr0 + v) * 2048 + gc] = f2b(val);
      }
    }
  }
}

// ---------------- skinny GEMM3 + tanh: [16384,2048]x[32,2048]^T -> d_out ----------------
__global__ __launch_bounds__(128) void gemm_skinny(
    const unsigned short* __restrict__ A,    // h2 [16384,2048] bf16
    const unsigned short* __restrict__ Bw,   // Weff [32,2048] bf16
    const float* __restrict__ beff,          // [32]
    float* __restrict__ out) {               // [16384,32] fp32
  const int t = threadIdx.x, lane = t & 63, w = t >> 6;
  const int lr = lane & 15, kh = lane >> 4;
  const int row0 = (blockIdx.x * 2 + w) * 16;
  f32x4 acc[2];
  acc[0] = (f32x4){0.f, 0.f, 0.f, 0.f};
  acc[1] = (f32x4){0.f, 0.f, 0.f, 0.f};

  const unsigned short* Arow = A  + (size_t)(row0 + lr) * HID + kh * 8;
  const unsigned short* B0   = Bw + (size_t)(lr) * HID + kh * 8;
  const unsigned short* B1   = Bw + (size_t)(16 + lr) * HID + kh * 8;

#pragma unroll 4
  for (int kt = 0; kt < HID; kt += 32) {
    bf16x8 a  = *reinterpret_cast<const bf16x8*>(Arow + kt);
    bf16x8 b0 = *reinterpret_cast<const bf16x8*>(B0 + kt);
    bf16x8 b1 = *reinterpret_cast<const bf16x8*>(B1 + kt);
    acc[0] = __builtin_amdgcn_mfma_f32_16x16x32_bf16(a, b0, acc[0], 0, 0, 0);
    acc[1] = __builtin_amdgcn_mfma_f32_16x16x32_bf16(a, b1, acc[1], 0, 0, 0);
  }
#pragma unroll
  for (int n = 0; n < 2; ++n)
#pragma unroll
    for (int v = 0; v < 4; ++v) {
      int row = row0 + kh * 4 + v;
      int col = n * 16 + lr;
      out[(size_t)row * ADIM + col] = tanhf(acc[n][v] + beff[col]);
    }
}

// ---------------- launch ----------------
extern "C" void kernel_launch(void* const* d_in, const int* in_sizes, int n_in,
                              void* d_out, int out_size, void* d_ws, size_t ws_size,
                              hipStream_t stream) {
  const float* state    = (const float*)d_in[0];
  const float* mean_enc = (const float*)d_in[1];
  const float* std_enc  = (const float*)d_in[2];
  const float* W1 = (const float*)d_in[3];
  const float* b1 = (const float*)d_in[4];
  const float* W2 = (const float*)d_in[5];
  const float* b2 = (const float*)d_in[6];
  const float* W3 = (const float*)d_in[7];
  const float* b3 = (const float*)d_in[8];
  const float* Wd = (const float*)d_in[9];
  const float* bd = (const float*)d_in[10];

  char* ws = (char*)d_ws;
  unsigned short* W1b   = (unsigned short*)(ws + 0);           //  5,242,880
  unsigned short* W2b   = (unsigned short*)(ws + 5242880);     //  8,388,608
  unsigned short* Weff  = (unsigned short*)(ws + 13631488);    //    131,072
  float*          beff  = (float*)(ws + 13762560);             //        128
  unsigned short* spine = (unsigned short*)(ws + 13762688);    // 41,943,040
  unsigned short* h1    = (unsigned short*)(ws + 55705728);    // 67,108,864
  unsigned short* h2    = (unsigned short*)(ws + 122814592);   // 67,108,864 -> end ~190MB

  // weight preprocessing
  f2b_kernel<<<5120, 256, 0, stream>>>(W1, (unsigned*)W1b, 1310720);
  f2b_kernel<<<8192, 256, 0, stream>>>(W2, (unsigned*)W2b, 2097152);
  weff_kernel<<<256, 256, 0, stream>>>(W3, Wd, Weff);
  beff_kernel<<<1, 64, 0, stream>>>(b3, Wd, bd, beff);

  // encoder
  encoder_kernel<<<(BATCH * SDIM) / 256, 256, 0, stream>>>(state, mean_enc, std_enc, (unsigned*)spine);

  // GEMM chain
  gemm256<<<512, 512, 0, stream>>>(spine, W1b, b1, h1, KSPINE, KSPINE / 128);
  gemm256<<<512, 512, 0, stream>>>(h1,    W2b, b2, h2, HID,    HID / 128);
  gemm_skinny<<<BATCH / 32, 128, 0, stream>>>(h2, Weff, beff, (float*)d_out);
}